// Round 10
// baseline (289.101 us; speedup 1.0000x reference)
//
#include <hip/hip_runtime.h>
#include <hip/hip_bf16.h>
#include <cstdint>
#include <cstddef>

// ---------- types / helpers ----------
typedef __attribute__((ext_vector_type(8))) short bf16x8;
typedef __attribute__((ext_vector_type(4))) float f32x4;

#define MFMA16(a, b, c) __builtin_amdgcn_mfma_f32_16x16x32_bf16((a), (b), (c), 0, 0, 0)
#define SBAR()  __builtin_amdgcn_s_barrier()
#define SCHED0() __builtin_amdgcn_sched_barrier(0)

static __device__ __forceinline__ unsigned short f2bf(float f) {
    union { float f; unsigned u; } v; v.f = f;
    unsigned r = v.u + 0x7fffu + ((v.u >> 16) & 1u);
    return (unsigned short)(r >> 16);
}

static __device__ __forceinline__ float bf2f(unsigned short u) {
    union { unsigned u; float f; } v; v.u = ((unsigned)u) << 16; return v.f;
}

static __device__ __forceinline__ float gelu_tanh(float x) {
    float z = 0.7978845608028654f * (x + 0.044715f * x * x * x);
    float a = fabsf(z);
    float e = __expf(-2.0f * a);
    float t = (1.0f - e) / (1.0f + e);
    t = (z < 0.0f) ? -t : t;
    return 0.5f * x * (1.0f + t);
}

static __device__ __forceinline__ void gload16(const void* g, void* l) {
    __builtin_amdgcn_global_load_lds((const __attribute__((address_space(1))) unsigned int*)g,
                                     (__attribute__((address_space(3))) unsigned int*)l,
                                     16, 0, 0);
}

// ---------- weight prep ----------
__global__ __launch_bounds__(256) void wcvt_kernel(const float* __restrict__ a, const float* __restrict__ b,
                                                   const float* __restrict__ c, const float* __restrict__ d,
                                                   unsigned short* __restrict__ o) {
    int i = blockIdx.x * 256 + threadIdx.x;
    int idx = i * 4;
    int which = idx >> 18;
    int off = idx & 262143;
    const float* src = (which == 0) ? a : (which == 1) ? b : (which == 2) ? c : d;
    float4 v = *(const float4*)(src + off);
    unsigned long long p = (unsigned long long)f2bf(v.x) | ((unsigned long long)f2bf(v.y) << 16)
                         | ((unsigned long long)f2bf(v.z) << 32) | ((unsigned long long)f2bf(v.w) << 48);
    *(unsigned long long*)(o + idx) = p;
}

// in: [L][R][C] f32 -> out: [L][C][R] bf16
__global__ __launch_bounds__(256) void wtrans_kernel(const float* __restrict__ in, unsigned short* __restrict__ out,
                                                     int R, int C) {
    __shared__ float tile[32][33];
    size_t lvl = blockIdx.z;
    in  += lvl * (size_t)R * C;
    out += lvl * (size_t)R * C;
    int c0 = blockIdx.x * 32, r0 = blockIdx.y * 32;
    int tx = threadIdx.x & 31, ty = threadIdx.x >> 5;
    #pragma unroll
    for (int ii = 0; ii < 4; ++ii) {
        int i = ty * 4 + ii;
        tile[i][tx] = in[(size_t)(r0 + i) * C + c0 + tx];
    }
    __syncthreads();
    #pragma unroll
    for (int jj = 0; jj < 4; ++jj) {
        int j = ty * 4 + jj;
        out[(size_t)(c0 + j) * R + r0 + tx] = f2bf(tile[tx][j]);
    }
}

// ---------- layernorm: f32 [rows][512] -> bf16 ----------
__global__ __launch_bounds__(256) void ln_kernel(const float* __restrict__ x,
                                                 const float* __restrict__ w,
                                                 const float* __restrict__ b,
                                                 unsigned short* __restrict__ out) {
    int tid = threadIdx.x, l = tid & 63, wv = tid >> 6;
    size_t row = (size_t)blockIdx.x * 4 + wv;
    const float* xr = x + row * 512 + l * 8;
    float4 v0 = *(const float4*)xr;
    float4 v1 = *(const float4*)(xr + 4);
    float vv[8] = {v0.x, v0.y, v0.z, v0.w, v1.x, v1.y, v1.z, v1.w};
    float s = 0.f, q = 0.f;
    #pragma unroll
    for (int j = 0; j < 8; ++j) { s += vv[j]; q += vv[j] * vv[j]; }
    #pragma unroll
    for (int off = 1; off < 64; off <<= 1) { s += __shfl_xor(s, off); q += __shfl_xor(q, off); }
    float mu = s * (1.0f / 512.0f);
    float rs = rsqrtf(q * (1.0f / 512.0f) - mu * mu + 1e-5f);
    union { unsigned short us[8]; uint4 u; } pk;
    #pragma unroll
    for (int j = 0; j < 8; ++j)
        pk.us[j] = f2bf((vv[j] - mu) * rs * w[l * 8 + j] + b[l * 8 + j]);
    *(uint4*)(out + row * 512 + l * 8) = pk.u;
}

// ---------- 256x256 GEMM, deep-pipelined 4-phase schedule ----------
// 512 threads / 8 waves (2Mx4N), per-wave 128x64 C, BK=64, 128 KB LDS dbuf.
// ALL FOUR half-tile stages of tile t+1 issue at phase 0 of tile t (buf[cur^1]
// is free: fully consumed at t-1's final barrier). Guards (per-wave vmcnt then
// SBAR -> cross-wave):
//   ph1-end: vmcnt(8)  forces all of tile t's 8 loads (issued 4 phases ago);
//            leaves t+1's 8 in flight.  [last tile: vmcnt(0)]
//   ph3-end: vmcnt(2)  forces B0,B1,A0 of t+1 (issued 3.5 phases ago);
//            leaves A1(t+1).            [last tile: no guard]
// So no load is needed sooner than ~3.5 phases (>= HBM latency) after issue.
// EPI: 0 ->bf16 ; 2 +bias,gelu->bf16 ; 5 bf16 partial (split-K via blockIdx.z)
template<int EPI>
__global__ __launch_bounds__(512, 2) void gemm256(
    const unsigned short* __restrict__ A,
    const unsigned short* __restrict__ Bt,
    int K, int lda, int ldb, int N,
    unsigned short* __restrict__ outb,
    const float* __restrict__ bias,
    size_t planeStride) {
    __shared__ bf16x8 As[2][2048];     // [buf][256 rows][8 slots] 32 KB each
    __shared__ bf16x8 Bs[2][2048];
    const int tid = threadIdx.x, l = tid & 63, w = tid >> 6;
    const int m0 = blockIdx.x * 256, n0 = blockIdx.y * 256;
    const int wr = (w >> 2) * 128, wc = (w & 3) * 64;
    const int srow = l >> 3;
    const int scol = ((l & 7) ^ srow) * 8;

    if constexpr (EPI == 5) {
        size_t z = blockIdx.z;
        A    += z * (size_t)K;         // K = per-plane K; lda spans full row
        Bt   += z * (size_t)K;
        outb += z * planeStride;
    }

    const int nkt = K >> 6;

    auto stageA = [&](int buf, int kt, int h) {
        const unsigned short* Ag = A + (size_t)m0 * lda + kt * 64;
        #pragma unroll
        for (int i = 0; i < 2; ++i) {
            int chunk = h * 8 + i * 16 + w;            // {w,16+w} or {8+w,24+w}
            int row = chunk * 8 + srow;
            gload16(Ag + (size_t)row * lda + scol, &As[buf][chunk * 64]);
        }
    };
    auto stageB = [&](int buf, int kt, int h) {
        const unsigned short* Bg = Bt + (size_t)n0 * ldb + kt * 64;
        #pragma unroll
        for (int i = 0; i < 2; ++i) {
            int chunk = ((i * 2 + (w >> 2)) << 3) | (h << 2) | (w & 3);
            int row = chunk * 8 + srow;
            gload16(Bg + (size_t)row * ldb + scol, &Bs[buf][chunk * 64]);
        }
    };

    f32x4 acc[8][4] = {};

    // prologue: full tile 0 (B0,B1,A0,A1); A1 may remain in flight (ph1 guard catches it)
    stageB(0, 0, 0); stageB(0, 0, 1); stageA(0, 0, 0); stageA(0, 0, 1);
    asm volatile("s_waitcnt vmcnt(2)" ::: "memory");
    SBAR(); SCHED0();

    int cur = 0;
    for (int kt = 0; kt < nkt; ++kt) {
        const bool more = (kt + 1 < nkt);
        bf16x8 af[4][2], bf_lo[2][2], bf_hi[2][2];

        // ---- phase 0: ds af(mi0-3)+bf_lo ; stage ALL of tile t+1 ; MFMA Q00 ----
        #pragma unroll
        for (int mi = 0; mi < 4; ++mi) {
            int r = wr + mi * 16 + (l & 15);
            #pragma unroll
            for (int kk = 0; kk < 2; ++kk)
                af[mi][kk] = As[cur][r * 8 + ((kk * 4 + (l >> 4)) ^ (r & 7))];
        }
        #pragma unroll
        for (int ni = 0; ni < 2; ++ni) {
            int r = wc + ni * 16 + (l & 15);
            #pragma unroll
            for (int kk = 0; kk < 2; ++kk)
                bf_lo[ni][kk] = Bs[cur][r * 8 + ((kk * 4 + (l >> 4)) ^ (r & 7))];
        }
        if (more) {
            stageB(cur ^ 1, kt + 1, 0);
            stageB(cur ^ 1, kt + 1, 1);
            stageA(cur ^ 1, kt + 1, 0);
            stageA(cur ^ 1, kt + 1, 1);
        }
        SBAR(); SCHED0();
        __builtin_amdgcn_s_setprio(1);
        #pragma unroll
        for (int mi = 0; mi < 4; ++mi)
            #pragma unroll
            for (int ni = 0; ni < 2; ++ni)
                #pragma unroll
                for (int kk = 0; kk < 2; ++kk)
                    acc[mi][ni] = MFMA16(af[mi][kk], bf_lo[ni][kk], acc[mi][ni]);
        __builtin_amdgcn_s_setprio(0);
        SCHED0(); SBAR();

        // ---- phase 1: ds bf_hi ; MFMA Q01 ; guard tile t fully landed ----
        #pragma unroll
        for (int ni = 0; ni < 2; ++ni) {
            int r = wc + (2 + ni) * 16 + (l & 15);
            #pragma unroll
            for (int kk = 0; kk < 2; ++kk)
                bf_hi[ni][kk] = Bs[cur][r * 8 + ((kk * 4 + (l >> 4)) ^ (r & 7))];
        }
        SBAR(); SCHED0();
        __builtin_amdgcn_s_setprio(1);
        #pragma unroll
        for (int mi = 0; mi < 4; ++mi)
            #pragma unroll
            for (int ni = 0; ni < 2; ++ni)
                #pragma unroll
                for (int kk = 0; kk < 2; ++kk)
                    acc[mi][2 + ni] = MFMA16(af[mi][kk], bf_hi[ni][kk], acc[mi][2 + ni]);
        __builtin_amdgcn_s_setprio(0);
        SCHED0();
        if (more) asm volatile("s_waitcnt vmcnt(8)" ::: "memory");
        else      asm volatile("s_waitcnt vmcnt(0)" ::: "memory");
        SBAR(); SCHED0();

        // ---- phase 2: ds af(mi4-7) ; MFMA Q10 ----
        #pragma unroll
        for (int mi = 0; mi < 4; ++mi) {
            int r = wr + 64 + mi * 16 + (l & 15);
            #pragma unroll
            for (int kk = 0; kk < 2; ++kk)
                af[mi][kk] = As[cur][r * 8 + ((kk * 4 + (l >> 4)) ^ (r & 7))];
        }
        SBAR(); SCHED0();
        __builtin_amdgcn_s_setprio(1);
        #pragma unroll
        for (int mi = 0; mi < 4; ++mi)
            #pragma unroll
            for (int ni = 0; ni < 2; ++ni)
                #pragma unroll
                for (int kk = 0; kk < 2; ++kk)
                    acc[4 + mi][ni] = MFMA16(af[mi][kk], bf_lo[ni][kk], acc[4 + mi][ni]);
        __builtin_amdgcn_s_setprio(0);
        SCHED0(); SBAR();

        // ---- phase 3: MFMA Q11 ; guard B0,B1,A0 of t+1 landed ----
        SBAR(); SCHED0();
        __builtin_amdgcn_s_setprio(1);
        #pragma unroll
        for (int mi = 0; mi < 4; ++mi)
            #pragma unroll
            for (int ni = 0; ni < 2; ++ni)
                #pragma unroll
                for (int kk = 0; kk < 2; ++kk)
                    acc[4 + mi][2 + ni] = MFMA16(af[mi][kk], bf_hi[ni][kk], acc[4 + mi][2 + ni]);
        __builtin_amdgcn_s_setprio(0);
        SCHED0();
        if (more) asm volatile("s_waitcnt vmcnt(2)" ::: "memory");
        SBAR(); SCHED0();

        cur ^= 1;
    }

    #pragma unroll
    for (int mi = 0; mi < 8; ++mi)
        #pragma unroll
        for (int ni = 0; ni < 4; ++ni) {
            int col = n0 + wc + ni * 16 + (l & 15);
            #pragma unroll
            for (int r = 0; r < 4; ++r) {
                int row = m0 + wr + mi * 16 + (l >> 4) * 4 + r;
                float v = acc[mi][ni][r];
                size_t idx = (size_t)row * N + col;
                if constexpr (EPI == 0) {
                    outb[idx] = f2bf(v);
                } else if constexpr (EPI == 2) {
                    v += bias[col];
                    outb[idx] = f2bf(gelu_tanh(v));
                } else {
                    outb[idx] = f2bf(v);   // bf16 partial
                }
            }
        }
}

// ---------- 128-tile GEMM (Wo only): R2 structure ----------
template<int EPI, int TN>
__global__ __launch_bounds__(256) void gemm_bt(
    const unsigned short* __restrict__ A,
    const unsigned short* __restrict__ Bt,
    int K, int lda, int ldb, int N,
    unsigned short* __restrict__ outb,
    float* __restrict__ outf,
    const float* __restrict__ bias,
    const float* __restrict__ resid) {
    constexpr int NI = TN / 32;
    constexpr int BCH = TN / 32;
    __shared__ bf16x8 As[2][1024];
    __shared__ bf16x8 Bs[2][TN * 8];
    const int tid = threadIdx.x, l = tid & 63, w = tid >> 6;
    const int m0 = blockIdx.x * 128, n0 = blockIdx.y * TN;
    const int wr = (w >> 1) * 64, wc = (w & 1) * (TN / 2);
    const int srow = l >> 3;
    const int scol = ((l & 7) ^ srow) * 8;

    const int nkt = K >> 6;
    auto stage = [&](int buf, int kt) {
        const unsigned short* Ag = A + (size_t)m0 * lda + kt * 64;
        const unsigned short* Bg = Bt + (size_t)n0 * ldb + kt * 64;
        #pragma unroll
        for (int i = 0; i < 4; ++i) {
            int chunk = i * 4 + w;
            int row = chunk * 8 + srow;
            gload16(Ag + (size_t)row * lda + scol, &As[buf][chunk * 64]);
        }
        #pragma unroll
        for (int i = 0; i < BCH; ++i) {
            int chunk = i * 4 + w;
            int row = chunk * 8 + srow;
            gload16(Bg + (size_t)row * ldb + scol, &Bs[buf][chunk * 64]);
        }
    };

    f32x4 acc[4][NI] = {};
    stage(0, 0);
    __syncthreads();
    int cur = 0;
    for (int kt = 0; kt < nkt; ++kt) {
        if (kt + 1 < nkt) stage(cur ^ 1, kt + 1);
        #pragma unroll
        for (int kk = 0; kk < 2; ++kk) {
            bf16x8 af[4], bfr[NI];
            #pragma unroll
            for (int mi = 0; mi < 4; ++mi) {
                int r = wr + mi * 16 + (l & 15);
                af[mi] = As[cur][r * 8 + ((kk * 4 + (l >> 4)) ^ (r & 7))];
            }
            #pragma unroll
            for (int ni = 0; ni < NI; ++ni) {
                int r = wc + ni * 16 + (l & 15);
                bfr[ni] = Bs[cur][r * 8 + ((kk * 4 + (l >> 4)) ^ (r & 7))];
            }
            #pragma unroll
            for (int mi = 0; mi < 4; ++mi)
                #pragma unroll
                for (int ni = 0; ni < NI; ++ni)
                    acc[mi][ni] = MFMA16(af[mi], bfr[ni], acc[mi][ni]);
        }
        __syncthreads();
        cur ^= 1;
    }

    #pragma unroll
    for (int mi = 0; mi < 4; ++mi)
        #pragma unroll
        for (int ni = 0; ni < NI; ++ni) {
            int col = n0 + wc + ni * 16 + (l & 15);
            #pragma unroll
            for (int r = 0; r < 4; ++r) {
                int row = m0 + wr + mi * 16 + (l >> 4) * 4 + r;
                float v = acc[mi][ni][r];
                size_t idx = (size_t)row * N + col;
                if constexpr (EPI == 1) {
                    outf[idx] = v + resid[idx];
                } else {
                    outb[idx] = f2bf(v);
                }
            }
        }
}

// ---------- split-K4 reduce ----------
template<bool FINAL>
__global__ __launch_bounds__(256) void reduce_down(const unsigned short* __restrict__ P,
                                                   const float* __restrict__ bias,
                                                   const float* __restrict__ resid,
                                                   unsigned short* __restrict__ outb,
                                                   float* __restrict__ outf) {
    size_t i = ((size_t)blockIdx.x * 256 + threadIdx.x) * 8;
    int col = (int)(i & 511);
    bf16x8 a0 = *(const bf16x8*)(P + i);
    bf16x8 a1 = *(const bf16x8*)(P + 4194304 + i);
    bf16x8 a2 = *(const bf16x8*)(P + 2 * 4194304 + i);
    bf16x8 a3 = *(const bf16x8*)(P + 3 * 4194304 + i);
    float4 b0 = *(const float4*)(bias + col);
    float4 b1 = *(const float4*)(bias + col + 4);
    float bs[8] = {b0.x, b0.y, b0.z, b0.w, b1.x, b1.y, b1.z, b1.w};
    float v[8];
    #pragma unroll
    for (int j = 0; j < 8; ++j)
        v[j] = (bf2f((unsigned short)a0[j]) + bf2f((unsigned short)a1[j]))
             + (bf2f((unsigned short)a2[j]) + bf2f((unsigned short)a3[j])) + bs[j];
    if constexpr (FINAL) {
        const float4 r0 = *(const float4*)(resid + i);
        const float4 r1 = *(const float4*)(resid + i + 4);
        float4 o0 = {v[0] + r0.x, v[1] + r0.y, v[2] + r0.z, v[3] + r0.w};
        float4 o1 = {v[4] + r1.x, v[5] + r1.y, v[6] + r1.z, v[7] + r1.w};
        *(float4*)(outf + i) = o0;
        *(float4*)(outf + i + 4) = o1;
    } else {
        union { unsigned short us[8]; uint4 u; } pk;
        #pragma unroll
        for (int j = 0; j < 8; ++j) pk.us[j] = f2bf(v[j]);
        *(uint4*)(outb + i) = pk.u;
    }
}

// ---------- attention A1 ----------
__global__ __launch_bounds__(256) void attn_u_kernel(
    const unsigned short* __restrict__ QKV,
    float* __restrict__ U) {
    const int c = blockIdx.x, h = blockIdx.y;
    const int tid = threadIdx.x, l = tid & 63, w = tid >> 6;
    __shared__ __align__(16) unsigned short Kt[64 * 256];
    __shared__ __align__(16) unsigned short Vt[64 * 256];
    for (int i = 0; i < 8; ++i) {
        int idx = i * 256 + tid;
        int tr = idx >> 3, g = idx & 7;
        int bb = tr >> 6, tl = tr & 63;
        size_t go = (size_t)(bb * 2048 + c * 64 + tl) * 1536 + h * 64 + g * 8;
        bf16x8 kv = *(const bf16x8*)(QKV + go + 512);
        bf16x8 vv = *(const bf16x8*)(QKV + go + 1024);
        #pragma unroll
        for (int j = 0; j < 8; ++j) {
            int d = g * 8 + j;
            int ts = tr ^ ((d & 7) << 3);
            Kt[d * 256 + ts] = (unsigned short)kv[j];
            Vt[d * 256 + ts] = (unsigned short)vv[j];
        }
    }
    __syncthreads();
    const int dr = (w >> 1) * 32, kc = (w & 1) * 32;
    f32x4 acc[2][2] = {};
    #pragma unroll
    for (int kk = 0; kk < 8; ++kk) {
        bf16x8 av[2], bk[2];
        #pragma unroll
        for (int mi = 0; mi < 2; ++mi) {
            int r = dr + mi * 16 + (l & 15);
            av[mi] = *(const bf16x8*)&Vt[r * 256 + ((kk * 32 + (l >> 4) * 8) ^ ((r & 7) << 3))];
        }
        #pragma unroll
        for (int ni = 0; ni < 2; ++ni) {
            int r = kc + ni * 16 + (l & 15);
            bk[ni] = *(const bf16x8*)&Kt[r * 256 + ((kk * 32 + (l >> 4) * 8) ^ ((r & 7) << 3))];
        }
        #pragma unroll
        for (int mi = 0; mi < 2; ++mi)
            #pragma unroll
            for (int ni = 0; ni < 2; ++ni)
                acc[mi][ni] = MFMA16(av[mi], bk[ni], acc[mi][ni]);
    }
    float* Uo = U + (size_t)(h * 32 + c) * 4096;
    #pragma unroll
    for (int mi = 0; mi < 2; ++mi)
        #pragma unroll
        for (int ni = 0; ni < 2; ++ni)
            #pragma unroll
            for (int r = 0; r < 4; ++r) {
                int d = dr + mi * 16 + (l >> 4) * 4 + r;
                int k2 = kc + ni * 16 + (l & 15);
                Uo[d * 64 + k2] = acc[mi][ni][r] * 0.25f;
            }
}

// ---------- attention A2 ----------
__global__ __launch_bounds__(256) void attn_scan_kernel(const float* __restrict__ U,
                                                        unsigned short* __restrict__ Mx) {
    int e = blockIdx.x * 256 + threadIdx.x;
    int h = blockIdx.y;
    const float* Ub = U + (size_t)h * 32 * 4096 + e;
    unsigned short* Mb = Mx + (size_t)h * 32 * 4096 + e;
    float a = 0.0f;
    #pragma unroll
    for (int c0 = 0; c0 < 32; c0 += 4) {
        float u0 = Ub[(c0 + 0) * 4096];
        float u1 = Ub[(c0 + 1) * 4096];
        float u2 = Ub[(c0 + 2) * 4096];
        float u3 = Ub[(c0 + 3) * 4096];
        Mb[(c0 + 0) * 4096] = f2bf(a); a += u0;
        Mb[(c0 + 1) * 4096] = f2bf(a); a += u1;
        Mb[(c0 + 2) * 4096] = f2bf(a); a += u2;
        Mb[(c0 + 3) * 4096] = f2bf(a); a += u3;
    }
}

// ---------- attention A3 ----------
__global__ __launch_bounds__(256) void attn_y_kernel(
    const unsigned short* __restrict__ QKV,
    const unsigned short* __restrict__ Mx,
    unsigned short* __restrict__ Y) {
    const int c = blockIdx.x, h = blockIdx.y;
    const int tid = threadIdx.x, l = tid & 63, w = tid >> 6;  // w == query batch
    __shared__ __align__(16) unsigned short Vt[64 * 256];
    __shared__ __align__(16) unsigned short Ss[4][64 * 64];

    for (int i = 0; i < 8; ++i) {
        int idx = i * 256 + tid;
        int tr = idx >> 3, g = idx & 7;
        int bb = tr >> 6, tl = tr & 63;
        bf16x8 vv = *(const bf16x8*)(QKV + ((size_t)(bb * 2048 + c * 64 + tl) * 1536 + 1024 + h * 64 + g * 8));
        #pragma unroll
        for (int j = 0; j < 8; ++j) {
            int d = g * 8 + j;
            Vt[d * 256 + (tr ^ ((d & 7) << 3))] = (unsigned short)vv[j];
        }
    }
    __syncthreads();

    f32x4 yacc[4][4] = {};

    bf16x8 qf[2][4];
    #pragma unroll
    for (int kk = 0; kk < 2; ++kk)
        #pragma unroll
        for (int ni = 0; ni < 4; ++ni) {
            int qloc = ni * 16 + (l & 15);
            qf[kk][ni] = *(const bf16x8*)(QKV + ((size_t)(w * 2048 + c * 64 + qloc) * 1536
                                                + h * 64 + kk * 32 + (l >> 4) * 8));
        }

    const unsigned short* Mrow = Mx + (size_t)(h * 32 + c) * 4096;
    #pragma unroll
    for (int kk = 0; kk < 2; ++kk) {
        bf16x8 am[4];
        #pragma unroll
        for (int mi = 0; mi < 4; ++mi) {
            int d = mi * 16 + (l & 15);
            am[mi] = *(const bf16x8*)(Mrow + d * 64 + kk * 32 + (l >> 4) * 8);
        }
        #pragma unroll
        for (int mi = 0; mi < 4; ++mi)
            #pragma unroll
            for (int ni = 0; ni < 4; ++ni)
                yacc[mi][ni] = MFMA16(am[mi], qf[kk][ni], yacc[mi][ni]);
    }

    unsigned short* Sw = &Ss[w][0];
    for (int tv = 0; tv < 4; ++tv) {
        #pragma unroll
        for (int th = 0; th < 2; ++th) {
            f32x4 sacc[2][4] = {};
            #pragma unroll
            for (int kk = 0; kk < 2; ++kk) {
                bf16x8 ak[2];
                #pragma unroll
                for (int mi = 0; mi < 2; ++mi) {
                    int tloc = th * 32 + mi * 16 + (l & 15);
                    ak[mi] = *(const bf16x8*)(QKV + ((size_t)(tv * 2048 + c * 64 + tloc) * 1536
                                                    + 512 + h * 64 + kk * 32 + (l >> 4) * 8));
                }
                #pragma unroll
                for (int mi = 0; mi < 2; ++mi)
                    #pragma unroll
                    for (int ni = 0; ni < 4; ++ni)
                        sacc[mi][ni] = MFMA16(ak[mi], qf[kk][ni], sacc[mi][ni]);
            }
            #pragma unroll
            for (int mi = 0; mi < 2; ++mi)
                #pragma unroll
                for (int ni = 0; ni < 4; ++ni) {
                    int tb = th * 32 + mi * 16 + (l >> 4) * 4;
                    int qcol = ni * 16 + (l & 15);
                    unsigned long long p = 0;
                    #pragma unroll
                    for (int r = 0; r < 4; ++r) {
                        float v = (tb + r <= qcol) ? sacc[mi][ni][r] * 0.25f : 0.0f;
                        p |= ((unsigned long long)f2bf(v)) << (16 * r);
                    }
                    int ts = tb ^ ((qcol & 7) << 3);
                    *(unsigned long long*)(Sw + qcol * 64 + ts) = p;
                }
        }
        #pragma unroll
        for (int kk2 = 0; kk2 < 2; ++kk2) {
            bf16x8 av[4], bs[4];
            #pragma unroll
            for (int mi = 0; mi < 4; ++mi) {
                int d = mi * 16 + (l & 15);
                av[mi] = *(const bf16x8*)&Vt[d * 256 + ((tv * 64 + kk2 * 32 + (l >> 4) * 8) ^ ((d & 7) << 3))];
            }
            #pragma unroll
            for (int ni = 0; ni < 4; ++ni) {
                int q = ni * 16 + (l & 15);
                bs[ni] = *(const bf16x8*)&Sw[q * 64 + ((kk2 * 32 + (l >> 4) * 8) ^ ((q & 7) << 3))];
            }
            #pragma unroll
            for (int mi = 0; mi < 4; ++mi)
                #pragma unroll
                for (int ni = 0; ni < 4; ++ni)
                    yacc[mi][ni] = MFMA16(av[mi], bs[ni], yacc[mi][ni]);
        }
    }

    #pragma unroll
    for (int mi = 0; mi < 4; ++mi)
        #pragma unroll
        for (int ni = 0; ni < 4; ++ni) {
            int qloc = ni * 16 + (l & 15);
            int d0 = mi * 16 + (l >> 4) * 4;
            unsigned long long p = 0;
            #pragma unroll
            for (int r = 0; r < 4; ++r)
                p |= ((unsigned long long)f2bf(yacc[mi][ni][r])) << (16 * r);
            *(unsigned long long*)(Y + ((size_t)(w * 2048 + c * 64 + qloc) * 512 + h * 64 + d0)) = p;
        }
}

// ---------- launch ----------
extern "C" void kernel_launch(void* const* d_in, const int* in_sizes, int n_in,
                              void* d_out, int out_size, void* d_ws, size_t ws_size,
                              hipStream_t stream) {
    const float* x    = (const float*)d_in[0];
    const float* Wq   = (const float*)d_in[1];
    const float* Wk   = (const float*)d_in[2];
    const float* Wv   = (const float*)d_in[3];
    const float* Wo   = (const float*)d_in[4];
    const float* ln1w = (const float*)d_in[5];
    const float* ln1b = (const float*)d_in[6];
    const float* ln2w = (const float*)d_in[7];
    const float* ln2b = (const float*)d_in[8];
    const float* W1   = (const float*)d_in[9];
    const float* b1   = (const float*)d_in[10];
    const float* W2   = (const float*)d_in[11];
    const float* b2   = (const float*)d_in[12];
    float* out = (float*)d_out;
    char* ws = (char*)d_ws;
    const size_t MB = 1024 * 1024;
    unsigned short* Wqb  = (unsigned short*)(ws + 0 * MB);   // Wq|Wk|Wv|Wo bf16
    unsigned short* W1t  = (unsigned short*)(ws + 2 * MB);   // [3][2048][512] bf16
    unsigned short* W2t  = (unsigned short*)(ws + 8 * MB);   // [3][512][2048] bf16
    unsigned short* hb   = (unsigned short*)(ws + 14 * MB);  // [8192][512] bf16
    unsigned short* QKVb = (unsigned short*)(ws + 22 * MB);  // [8192][1536] bf16
    unsigned short* Yb   = (unsigned short*)(ws + 46 * MB);  // [8192][512] bf16
    unsigned short* tb   = (unsigned short*)(ws + 22 * MB);  // [8192][2048] bf16 (aliases QKV+Y)
    float*          x2   = (float*)(ws + 54 * MB);           // [8192][512] f32
    float*          U    = (float*)(ws + 70 * MB);           // [8][32][64][64] f32
    unsigned short* Mx   = (unsigned short*)(ws + 74 * MB);  // [8][32][64][64] bf16
    unsigned short* P    = (unsigned short*)(ws + 76 * MB);  // 4 x [8192][512] bf16 partials (32 MiB)

    const bool splitk = ws_size >= (size_t)108 * MB;

    wcvt_kernel<<<1024, 256, 0, stream>>>(Wq, Wk, Wv, Wo, Wqb);
    wtrans_kernel<<<dim3(64, 16, 3), 256, 0, stream>>>(W1, W1t, 512, 2048);
    wtrans_kernel<<<dim3(16, 64, 3), 256, 0, stream>>>(W2, W2t, 2048, 512);

    ln_kernel<<<2048, 256, 0, stream>>>(x, ln1w, ln1b, hb);

    // fused QKV: [8192,512] @ [1536,512]^T, 256^2 tiles: grid (32,6)
    gemm256<0><<<dim3(32, 6), 512, 0, stream>>>(hb, Wqb, 512, 512, 512, 1536,
                                                QKVb, nullptr, 0);

    attn_u_kernel<<<dim3(32, 8), 256, 0, stream>>>(QKVb, U);
    attn_scan_kernel<<<dim3(16, 8), 256, 0, stream>>>(U, Mx);
    attn_y_kernel<<<dim3(32, 8), 256, 0, stream>>>(QKVb, Mx, Yb);

    // Wo projection + residual: 128-tile (R2 config), grid (64,4)
    gemm_bt<1, 128><<<dim3(64, 4), 256, 0, stream>>>(Yb, Wqb + 3 * 262144, 512, 512, 512, 512,
                                                     nullptr, x2, nullptr, x);

    ln_kernel<<<2048, 256, 0, stream>>>(x2, ln2w, ln2b, hb);

    for (int lvl = 0; lvl < 3; ++lvl) {
        // up-proj 256^2: grid (32,8) = 256 blocks
        gemm256<2><<<dim3(32, 8), 512, 0, stream>>>(hb, W1t + (size_t)lvl * 1048576,
                                                    512, 512, 512, 2048,
                                                    tb, b1 + lvl * 2048, 0);
        if (splitk) {
            // down-proj split-K4, 256^2: grid (32,2,4) = 256 blocks, K=512/plane
            gemm256<5><<<dim3(32, 2, 4), 512, 0, stream>>>(tb, W2t + (size_t)lvl * 1048576,
                                                           512, 2048, 2048, 512,
                                                           P, nullptr, (size_t)8192 * 512);
            if (lvl < 2)
                reduce_down<false><<<2048, 256, 0, stream>>>(P, b2 + lvl * 512, nullptr, hb, nullptr);
            else
                reduce_down<true><<<2048, 256, 0, stream>>>(P, b2 + lvl * 512, x2, nullptr, out);
        } else {
            gemm256<5><<<dim3(32, 2, 1), 512, 0, stream>>>(tb, W2t + (size_t)lvl * 1048576,
                                                           2048, 2048, 2048, 512,
                                                           P, nullptr, 0);
            if (lvl < 2)
                reduce_down<false><<<2048, 256, 0, stream>>>(P, b2 + lvl * 512, nullptr, hb, nullptr);
            else
                reduce_down<true><<<2048, 256, 0, stream>>>(P, b2 + lvl * 512, x2, nullptr, out);
        }
    }
}

// Round 11
// 284.745 us; speedup vs baseline: 1.0153x; 1.0153x over previous
//
#include <hip/hip_runtime.h>
#include <hip/hip_bf16.h>
#include <cstdint>
#include <cstddef>

// ---------- types / helpers ----------
typedef __attribute__((ext_vector_type(8))) short bf16x8;
typedef __attribute__((ext_vector_type(4))) float f32x4;

#define MFMA16(a, b, c) __builtin_amdgcn_mfma_f32_16x16x32_bf16((a), (b), (c), 0, 0, 0)

static __device__ __forceinline__ unsigned short f2bf(float f) {
    union { float f; unsigned u; } v; v.f = f;
    unsigned r = v.u + 0x7fffu + ((v.u >> 16) & 1u);
    return (unsigned short)(r >> 16);
}

static __device__ __forceinline__ float bf2f(unsigned short u) {
    union { unsigned u; float f; } v; v.u = ((unsigned)u) << 16; return v.f;
}

static __device__ __forceinline__ float gelu_tanh(float x) {
    float z = 0.7978845608028654f * (x + 0.044715f * x * x * x);
    float a = fabsf(z);
    float e = __expf(-2.0f * a);
    float t = (1.0f - e) / (1.0f + e);
    t = (z < 0.0f) ? -t : t;
    return 0.5f * x * (1.0f + t);
}

static __device__ __forceinline__ void gload16(const void* g, void* l) {
    __builtin_amdgcn_global_load_lds((const __attribute__((address_space(1))) unsigned int*)g,
                                     (__attribute__((address_space(3))) unsigned int*)l,
                                     16, 0, 0);
}

// ---------- merged weight prep ----------
// blocks [0,1024): Wq|Wk|Wv|Wo f32 -> bf16 (4x262144 elems, 4/thread)
// blocks [1024,4096): W1 [3][512][2048] -> W1t [3][2048][512] bf16
// blocks [4096,7168): W2 [3][2048][512] -> W2t [3][512][2048] bf16
__global__ __launch_bounds__(256) void prep_kernel(
    const float* __restrict__ Wq, const float* __restrict__ Wk,
    const float* __restrict__ Wv, const float* __restrict__ Wo,
    unsigned short* __restrict__ Wqb,
    const float* __restrict__ W1, unsigned short* __restrict__ W1t,
    const float* __restrict__ W2, unsigned short* __restrict__ W2t) {
    int b = blockIdx.x;
    if (b < 1024) {
        int i = b * 256 + threadIdx.x;
        int idx = i * 4;
        int which = idx >> 18;
        int off = idx & 262143;
        const float* src = (which == 0) ? Wq : (which == 1) ? Wk : (which == 2) ? Wv : Wo;
        float4 v = *(const float4*)(src + off);
        unsigned long long p = (unsigned long long)f2bf(v.x) | ((unsigned long long)f2bf(v.y) << 16)
                             | ((unsigned long long)f2bf(v.z) << 32) | ((unsigned long long)f2bf(v.w) << 48);
        *(unsigned long long*)(Wqb + idx) = p;
        return;
    }
    __shared__ float tile[32][33];
    const float* in; unsigned short* out;
    int R, C, c0, r0;
    if (b < 4096) {
        int t = b - 1024; int lvl = t >> 10; int r = t & 1023;
        R = 512; C = 2048;
        in  = W1 + (size_t)lvl * R * C;  out = W1t + (size_t)lvl * R * C;
        c0 = (r & 63) * 32; r0 = (r >> 6) * 32;
    } else {
        int t = b - 4096; int lvl = t >> 10; int r = t & 1023;
        R = 2048; C = 512;
        in  = W2 + (size_t)lvl * R * C;  out = W2t + (size_t)lvl * R * C;
        c0 = (r & 15) * 32; r0 = (r >> 4) * 32;
    }
    int tx = threadIdx.x & 31, ty = threadIdx.x >> 5;
    #pragma unroll
    for (int ii = 0; ii < 4; ++ii) {
        int i = ty * 4 + ii;
        tile[i][tx] = in[(size_t)(r0 + i) * C + c0 + tx];
    }
    __syncthreads();
    #pragma unroll
    for (int jj = 0; jj < 4; ++jj) {
        int j = ty * 4 + jj;
        out[(size_t)(c0 + j) * R + r0 + tx] = f2bf(tile[tx][j]);
    }
}

// ---------- layernorm: f32 [rows][512] -> bf16 ----------
__global__ __launch_bounds__(256) void ln_kernel(const float* __restrict__ x,
                                                 const float* __restrict__ w,
                                                 const float* __restrict__ b,
                                                 unsigned short* __restrict__ out) {
    int tid = threadIdx.x, l = tid & 63, wv = tid >> 6;
    size_t row = (size_t)blockIdx.x * 4 + wv;
    const float* xr = x + row * 512 + l * 8;
    float4 v0 = *(const float4*)xr;
    float4 v1 = *(const float4*)(xr + 4);
    float vv[8] = {v0.x, v0.y, v0.z, v0.w, v1.x, v1.y, v1.z, v1.w};
    float s = 0.f, q = 0.f;
    #pragma unroll
    for (int j = 0; j < 8; ++j) { s += vv[j]; q += vv[j] * vv[j]; }
    #pragma unroll
    for (int off = 1; off < 64; off <<= 1) { s += __shfl_xor(s, off); q += __shfl_xor(q, off); }
    float mu = s * (1.0f / 512.0f);
    float rs = rsqrtf(q * (1.0f / 512.0f) - mu * mu + 1e-5f);
    union { unsigned short us[8]; uint4 u; } pk;
    #pragma unroll
    for (int j = 0; j < 8; ++j)
        pk.us[j] = f2bf((vv[j] - mu) * rs * w[l * 8 + j] + b[l * 8 + j]);
    *(uint4*)(out + row * 512 + l * 8) = pk.u;
}

// ---------- 256x256 GEMM (R8 2-phase loop) + XCD panel mapping ----------
// XMAP=0: logical mapping (m0=bx,n0=by; z=bz for EPI5).
// XMAP=1: B-panel-per-XCD for ny==8 grids: hw id = bx+by*gx;
//         n0=(id&7)*256 -> XCD k owns ONE 2MB B-panel (L2-resident),
//         m0=(id>>3)*256 streams A.
// XMAP=2: same for down-proj's 8 (y,z) combos: n0=(id&1)*256, z=(id&7)>>1.
// EPI: 0 ->bf16 ; 2 +bias,gelu->bf16 ; 5 bf16 partial (split-K)
template<int EPI, int XMAP>
__global__ __launch_bounds__(512, 2) void gemm256(
    const unsigned short* __restrict__ A,
    const unsigned short* __restrict__ Bt,
    int K, int lda, int ldb, int N,
    unsigned short* __restrict__ outb,
    const float* __restrict__ bias,
    size_t planeStride) {
    __shared__ bf16x8 As[2][2048];
    __shared__ bf16x8 Bs[2][2048];
    const int tid = threadIdx.x, l = tid & 63, w = tid >> 6;
    int m0, n0;
    size_t z = 0;
    if constexpr (XMAP == 1) {
        int id = blockIdx.x + blockIdx.y * gridDim.x;
        n0 = (id & 7) * 256; m0 = (id >> 3) * 256;
    } else if constexpr (XMAP == 2) {
        int id = blockIdx.x + blockIdx.y * gridDim.x + blockIdx.z * gridDim.x * gridDim.y;
        int k8 = id & 7;
        n0 = (k8 & 1) * 256; z = (size_t)(k8 >> 1); m0 = (id >> 3) * 256;
    } else {
        m0 = blockIdx.x * 256; n0 = blockIdx.y * 256;
        if constexpr (EPI == 5) z = blockIdx.z;
    }
    const int wr = (w >> 2) * 128, wc = (w & 3) * 64;
    const int srow = l >> 3;
    const int scol = ((l & 7) ^ srow) * 8;

    if constexpr (EPI == 5) {
        A    += z * (size_t)K;         // K = per-plane K; lda spans full row
        Bt   += z * (size_t)K;
        outb += z * planeStride;
    }

    const int nkt = K >> 6;
    auto stage = [&](int buf, int kt) {
        const unsigned short* Ag = A + (size_t)m0 * lda + kt * 64;
        const unsigned short* Bg = Bt + (size_t)n0 * ldb + kt * 64;
        #pragma unroll
        for (int i = 0; i < 4; ++i) {
            int chunk = i * 8 + w;
            int row = chunk * 8 + srow;
            gload16(Ag + (size_t)row * lda + scol, &As[buf][chunk * 64]);
            gload16(Bg + (size_t)row * ldb + scol, &Bs[buf][chunk * 64]);
        }
    };

    f32x4 acc[8][4] = {};
    stage(0, 0);
    __syncthreads();
    int cur = 0;
    for (int kt = 0; kt < nkt; ++kt) {
        if (kt + 1 < nkt) stage(cur ^ 1, kt + 1);
        #pragma unroll
        for (int kk = 0; kk < 2; ++kk) {
            bf16x8 af[8], bfr[4];
            #pragma unroll
            for (int mi = 0; mi < 8; ++mi) {
                int r = wr + mi * 16 + (l & 15);
                af[mi] = As[cur][r * 8 + ((kk * 4 + (l >> 4)) ^ (r & 7))];
            }
            #pragma unroll
            for (int ni = 0; ni < 4; ++ni) {
                int r = wc + ni * 16 + (l & 15);
                bfr[ni] = Bs[cur][r * 8 + ((kk * 4 + (l >> 4)) ^ (r & 7))];
            }
            #pragma unroll
            for (int mi = 0; mi < 8; ++mi)
                #pragma unroll
                for (int ni = 0; ni < 4; ++ni)
                    acc[mi][ni] = MFMA16(af[mi], bfr[ni], acc[mi][ni]);
        }
        __syncthreads();
        cur ^= 1;
    }

    #pragma unroll
    for (int mi = 0; mi < 8; ++mi)
        #pragma unroll
        for (int ni = 0; ni < 4; ++ni) {
            int col = n0 + wc + ni * 16 + (l & 15);
            #pragma unroll
            for (int r = 0; r < 4; ++r) {
                int row = m0 + wr + mi * 16 + (l >> 4) * 4 + r;
                float v = acc[mi][ni][r];
                size_t idx = (size_t)row * N + col;
                if constexpr (EPI == 0) {
                    outb[idx] = f2bf(v);
                } else if constexpr (EPI == 2) {
                    v += bias[col];
                    outb[idx] = f2bf(gelu_tanh(v));
                } else {
                    outb[idx] = f2bf(v);   // bf16 partial
                }
            }
        }
}

// ---------- 128-tile GEMM (Wo only): R2 structure ----------
template<int EPI, int TN>
__global__ __launch_bounds__(256) void gemm_bt(
    const unsigned short* __restrict__ A,
    const unsigned short* __restrict__ Bt,
    int K, int lda, int ldb, int N,
    unsigned short* __restrict__ outb,
    float* __restrict__ outf,
    const float* __restrict__ bias,
    const float* __restrict__ resid) {
    constexpr int NI = TN / 32;
    constexpr int BCH = TN / 32;
    __shared__ bf16x8 As[2][1024];
    __shared__ bf16x8 Bs[2][TN * 8];
    const int tid = threadIdx.x, l = tid & 63, w = tid >> 6;
    const int m0 = blockIdx.x * 128, n0 = blockIdx.y * TN;
    const int wr = (w >> 1) * 64, wc = (w & 1) * (TN / 2);
    const int srow = l >> 3;
    const int scol = ((l & 7) ^ srow) * 8;

    const int nkt = K >> 6;
    auto stage = [&](int buf, int kt) {
        const unsigned short* Ag = A + (size_t)m0 * lda + kt * 64;
        const unsigned short* Bg = Bt + (size_t)n0 * ldb + kt * 64;
        #pragma unroll
        for (int i = 0; i < 4; ++i) {
            int chunk = i * 4 + w;
            int row = chunk * 8 + srow;
            gload16(Ag + (size_t)row * lda + scol, &As[buf][chunk * 64]);
        }
        #pragma unroll
        for (int i = 0; i < BCH; ++i) {
            int chunk = i * 4 + w;
            int row = chunk * 8 + srow;
            gload16(Bg + (size_t)row * ldb + scol, &Bs[buf][chunk * 64]);
        }
    };

    f32x4 acc[4][NI] = {};
    stage(0, 0);
    __syncthreads();
    int cur = 0;
    for (int kt = 0; kt < nkt; ++kt) {
        if (kt + 1 < nkt) stage(cur ^ 1, kt + 1);
        #pragma unroll
        for (int kk = 0; kk < 2; ++kk) {
            bf16x8 af[4], bfr[NI];
            #pragma unroll
            for (int mi = 0; mi < 4; ++mi) {
                int r = wr + mi * 16 + (l & 15);
                af[mi] = As[cur][r * 8 + ((kk * 4 + (l >> 4)) ^ (r & 7))];
            }
            #pragma unroll
            for (int ni = 0; ni < NI; ++ni) {
                int r = wc + ni * 16 + (l & 15);
                bfr[ni] = Bs[cur][r * 8 + ((kk * 4 + (l >> 4)) ^ (r & 7))];
            }
            #pragma unroll
            for (int mi = 0; mi < 4; ++mi)
                #pragma unroll
                for (int ni = 0; ni < NI; ++ni)
                    acc[mi][ni] = MFMA16(af[mi], bfr[ni], acc[mi][ni]);
        }
        __syncthreads();
        cur ^= 1;
    }

    #pragma unroll
    for (int mi = 0; mi < 4; ++mi)
        #pragma unroll
        for (int ni = 0; ni < NI; ++ni) {
            int col = n0 + wc + ni * 16 + (l & 15);
            #pragma unroll
            for (int r = 0; r < 4; ++r) {
                int row = m0 + wr + mi * 16 + (l >> 4) * 4 + r;
                float v = acc[mi][ni][r];
                size_t idx = (size_t)row * N + col;
                if constexpr (EPI == 1) {
                    outf[idx] = v + resid[idx];
                } else {
                    outb[idx] = f2bf(v);
                }
            }
        }
}

// ---------- split-K4 reduce ----------
template<bool FINAL>
__global__ __launch_bounds__(256) void reduce_down(const unsigned short* __restrict__ P,
                                                   const float* __restrict__ bias,
                                                   const float* __restrict__ resid,
                                                   unsigned short* __restrict__ outb,
                                                   float* __restrict__ outf) {
    size_t i = ((size_t)blockIdx.x * 256 + threadIdx.x) * 8;
    int col = (int)(i & 511);
    bf16x8 a0 = *(const bf16x8*)(P + i);
    bf16x8 a1 = *(const bf16x8*)(P + 4194304 + i);
    bf16x8 a2 = *(const bf16x8*)(P + 2 * 4194304 + i);
    bf16x8 a3 = *(const bf16x8*)(P + 3 * 4194304 + i);
    float4 b0 = *(const float4*)(bias + col);
    float4 b1 = *(const float4*)(bias + col + 4);
    float bs[8] = {b0.x, b0.y, b0.z, b0.w, b1.x, b1.y, b1.z, b1.w};
    float v[8];
    #pragma unroll
    for (int j = 0; j < 8; ++j)
        v[j] = (bf2f((unsigned short)a0[j]) + bf2f((unsigned short)a1[j]))
             + (bf2f((unsigned short)a2[j]) + bf2f((unsigned short)a3[j])) + bs[j];
    if constexpr (FINAL) {
        const float4 r0 = *(const float4*)(resid + i);
        const float4 r1 = *(const float4*)(resid + i + 4);
        float4 o0 = {v[0] + r0.x, v[1] + r0.y, v[2] + r0.z, v[3] + r0.w};
        float4 o1 = {v[4] + r1.x, v[5] + r1.y, v[6] + r1.z, v[7] + r1.w};
        *(float4*)(outf + i) = o0;
        *(float4*)(outf + i + 4) = o1;
    } else {
        union { unsigned short us[8]; uint4 u; } pk;
        #pragma unroll
        for (int j = 0; j < 8; ++j) pk.us[j] = f2bf(v[j]);
        *(uint4*)(outb + i) = pk.u;
    }
}

// ---------- attention A1 ----------
__global__ __launch_bounds__(256) void attn_u_kernel(
    const unsigned short* __restrict__ QKV,
    float* __restrict__ U) {
    const int c = blockIdx.x, h = blockIdx.y;
    const int tid = threadIdx.x, l = tid & 63, w = tid >> 6;
    __shared__ __align__(16) unsigned short Kt[64 * 256];
    __shared__ __align__(16) unsigned short Vt[64 * 256];
    for (int i = 0; i < 8; ++i) {
        int idx = i * 256 + tid;
        int tr = idx >> 3, g = idx & 7;
        int bb = tr >> 6, tl = tr & 63;
        size_t go = (size_t)(bb * 2048 + c * 64 + tl) * 1536 + h * 64 + g * 8;
        bf16x8 kv = *(const bf16x8*)(QKV + go + 512);
        bf16x8 vv = *(const bf16x8*)(QKV + go + 1024);
        #pragma unroll
        for (int j = 0; j < 8; ++j) {
            int d = g * 8 + j;
            int ts = tr ^ ((d & 7) << 3);
            Kt[d * 256 + ts] = (unsigned short)kv[j];
            Vt[d * 256 + ts] = (unsigned short)vv[j];
        }
    }
    __syncthreads();
    const int dr = (w >> 1) * 32, kc = (w & 1) * 32;
    f32x4 acc[2][2] = {};
    #pragma unroll
    for (int kk = 0; kk < 8; ++kk) {
        bf16x8 av[2], bk[2];
        #pragma unroll
        for (int mi = 0; mi < 2; ++mi) {
            int r = dr + mi * 16 + (l & 15);
            av[mi] = *(const bf16x8*)&Vt[r * 256 + ((kk * 32 + (l >> 4) * 8) ^ ((r & 7) << 3))];
        }
        #pragma unroll
        for (int ni = 0; ni < 2; ++ni) {
            int r = kc + ni * 16 + (l & 15);
            bk[ni] = *(const bf16x8*)&Kt[r * 256 + ((kk * 32 + (l >> 4) * 8) ^ ((r & 7) << 3))];
        }
        #pragma unroll
        for (int mi = 0; mi < 2; ++mi)
            #pragma unroll
            for (int ni = 0; ni < 2; ++ni)
                acc[mi][ni] = MFMA16(av[mi], bk[ni], acc[mi][ni]);
    }
    float* Uo = U + (size_t)(h * 32 + c) * 4096;
    #pragma unroll
    for (int mi = 0; mi < 2; ++mi)
        #pragma unroll
        for (int ni = 0; ni < 2; ++ni)
            #pragma unroll
            for (int r = 0; r < 4; ++r) {
                int d = dr + mi * 16 + (l >> 4) * 4 + r;
                int k2 = kc + ni * 16 + (l & 15);
                Uo[d * 64 + k2] = acc[mi][ni][r] * 0.25f;
            }
}

// ---------- attention A2 ----------
__global__ __launch_bounds__(256) void attn_scan_kernel(const float* __restrict__ U,
                                                        unsigned short* __restrict__ Mx) {
    int e = blockIdx.x * 256 + threadIdx.x;
    int h = blockIdx.y;
    const float* Ub = U + (size_t)h * 32 * 4096 + e;
    unsigned short* Mb = Mx + (size_t)h * 32 * 4096 + e;
    float a = 0.0f;
    #pragma unroll
    for (int c0 = 0; c0 < 32; c0 += 4) {
        float u0 = Ub[(c0 + 0) * 4096];
        float u1 = Ub[(c0 + 1) * 4096];
        float u2 = Ub[(c0 + 2) * 4096];
        float u3 = Ub[(c0 + 3) * 4096];
        Mb[(c0 + 0) * 4096] = f2bf(a); a += u0;
        Mb[(c0 + 1) * 4096] = f2bf(a); a += u1;
        Mb[(c0 + 2) * 4096] = f2bf(a); a += u2;
        Mb[(c0 + 3) * 4096] = f2bf(a); a += u3;
    }
}

// ---------- attention A3 ----------
__global__ __launch_bounds__(256) void attn_y_kernel(
    const unsigned short* __restrict__ QKV,
    const unsigned short* __restrict__ Mx,
    unsigned short* __restrict__ Y) {
    const int c = blockIdx.x, h = blockIdx.y;
    const int tid = threadIdx.x, l = tid & 63, w = tid >> 6;  // w == query batch
    __shared__ __align__(16) unsigned short Vt[64 * 256];
    __shared__ __align__(16) unsigned short Ss[4][64 * 64];

    for (int i = 0; i < 8; ++i) {
        int idx = i * 256 + tid;
        int tr = idx >> 3, g = idx & 7;
        int bb = tr >> 6, tl = tr & 63;
        bf16x8 vv = *(const bf16x8*)(QKV + ((size_t)(bb * 2048 + c * 64 + tl) * 1536 + 1024 + h * 64 + g * 8));
        #pragma unroll
        for (int j = 0; j < 8; ++j) {
            int d = g * 8 + j;
            Vt[d * 256 + (tr ^ ((d & 7) << 3))] = (unsigned short)vv[j];
        }
    }
    __syncthreads();

    f32x4 yacc[4][4] = {};

    bf16x8 qf[2][4];
    #pragma unroll
    for (int kk = 0; kk < 2; ++kk)
        #pragma unroll
        for (int ni = 0; ni < 4; ++ni) {
            int qloc = ni * 16 + (l & 15);
            qf[kk][ni] = *(const bf16x8*)(QKV + ((size_t)(w * 2048 + c * 64 + qloc) * 1536
                                                + h * 64 + kk * 32 + (l >> 4) * 8));
        }

    const unsigned short* Mrow = Mx + (size_t)(h * 32 + c) * 4096;
    #pragma unroll
    for (int kk = 0; kk < 2; ++kk) {
        bf16x8 am[4];
        #pragma unroll
        for (int mi = 0; mi < 4; ++mi) {
            int d = mi * 16 + (l & 15);
            am[mi] = *(const bf16x8*)(Mrow + d * 64 + kk * 32 + (l >> 4) * 8);
        }
        #pragma unroll
        for (int mi = 0; mi < 4; ++mi)
            #pragma unroll
            for (int ni = 0; ni < 4; ++ni)
                yacc[mi][ni] = MFMA16(am[mi], qf[kk][ni], yacc[mi][ni]);
    }

    unsigned short* Sw = &Ss[w][0];
    for (int tv = 0; tv < 4; ++tv) {
        #pragma unroll
        for (int th = 0; th < 2; ++th) {
            f32x4 sacc[2][4] = {};
            #pragma unroll
            for (int kk = 0; kk < 2; ++kk) {
                bf16x8 ak[2];
                #pragma unroll
                for (int mi = 0; mi < 2; ++mi) {
                    int tloc = th * 32 + mi * 16 + (l & 15);
                    ak[mi] = *(const bf16x8*)(QKV + ((size_t)(tv * 2048 + c * 64 + tloc) * 1536
                                                    + 512 + h * 64 + kk * 32 + (l >> 4) * 8));
                }
                #pragma unroll
                for (int mi = 0; mi < 2; ++mi)
                    #pragma unroll
                    for (int ni = 0; ni < 4; ++ni)
                        sacc[mi][ni] = MFMA16(ak[mi], qf[kk][ni], sacc[mi][ni]);
            }
            #pragma unroll
            for (int mi = 0; mi < 2; ++mi)
                #pragma unroll
                for (int ni = 0; ni < 4; ++ni) {
                    int tb = th * 32 + mi * 16 + (l >> 4) * 4;
                    int qcol = ni * 16 + (l & 15);
                    unsigned long long p = 0;
                    #pragma unroll
                    for (int r = 0; r < 4; ++r) {
                        float v = (tb + r <= qcol) ? sacc[mi][ni][r] * 0.25f : 0.0f;
                        p |= ((unsigned long long)f2bf(v)) << (16 * r);
                    }
                    int ts = tb ^ ((qcol & 7) << 3);
                    *(unsigned long long*)(Sw + qcol * 64 + ts) = p;
                }
        }
        #pragma unroll
        for (int kk2 = 0; kk2 < 2; ++kk2) {
            bf16x8 av[4], bs[4];
            #pragma unroll
            for (int mi = 0; mi < 4; ++mi) {
                int d = mi * 16 + (l & 15);
                av[mi] = *(const bf16x8*)&Vt[d * 256 + ((tv * 64 + kk2 * 32 + (l >> 4) * 8) ^ ((d & 7) << 3))];
            }
            #pragma unroll
            for (int ni = 0; ni < 4; ++ni) {
                int q = ni * 16 + (l & 15);
                bs[ni] = *(const bf16x8*)&Sw[q * 64 + ((kk2 * 32 + (l >> 4) * 8) ^ ((q & 7) << 3))];
            }
            #pragma unroll
            for (int mi = 0; mi < 4; ++mi)
                #pragma unroll
                for (int ni = 0; ni < 4; ++ni)
                    yacc[mi][ni] = MFMA16(av[mi], bs[ni], yacc[mi][ni]);
        }
    }

    #pragma unroll
    for (int mi = 0; mi < 4; ++mi)
        #pragma unroll
        for (int ni = 0; ni < 4; ++ni) {
            int qloc = ni * 16 + (l & 15);
            int d0 = mi * 16 + (l >> 4) * 4;
            unsigned long long p = 0;
            #pragma unroll
            for (int r = 0; r < 4; ++r)
                p |= ((unsigned long long)f2bf(yacc[mi][ni][r])) << (16 * r);
            *(unsigned long long*)(Y + ((size_t)(w * 2048 + c * 64 + qloc) * 512 + h * 64 + d0)) = p;
        }
}

// ---------- launch ----------
extern "C" void kernel_launch(void* const* d_in, const int* in_sizes, int n_in,
                              void* d_out, int out_size, void* d_ws, size_t ws_size,
                              hipStream_t stream) {
    const float* x    = (const float*)d_in[0];
    const float* Wq   = (const float*)d_in[1];
    const float* Wk   = (const float*)d_in[2];
    const float* Wv   = (const float*)d_in[3];
    const float* Wo   = (const float*)d_in[4];
    const float* ln1w = (const float*)d_in[5];
    const float* ln1b = (const float*)d_in[6];
    const float* ln2w = (const float*)d_in[7];
    const float* ln2b = (const float*)d_in[8];
    const float* W1   = (const float*)d_in[9];
    const float* b1   = (const float*)d_in[10];
    const float* W2   = (const float*)d_in[11];
    const float* b2   = (const float*)d_in[12];
    float* out = (float*)d_out;
    char* ws = (char*)d_ws;
    const size_t MB = 1024 * 1024;
    unsigned short* Wqb  = (unsigned short*)(ws + 0 * MB);   // Wq|Wk|Wv|Wo bf16
    unsigned short* W1t  = (unsigned short*)(ws + 2 * MB);   // [3][2048][512] bf16
    unsigned short* W2t  = (unsigned short*)(ws + 8 * MB);   // [3][512][2048] bf16
    unsigned short* hb   = (unsigned short*)(ws + 14 * MB);  // [8192][512] bf16
    unsigned short* QKVb = (unsigned short*)(ws + 22 * MB);  // [8192][1536] bf16
    unsigned short* Yb   = (unsigned short*)(ws + 46 * MB);  // [8192][512] bf16
    unsigned short* tb   = (unsigned short*)(ws + 22 * MB);  // [8192][2048] bf16 (aliases QKV+Y)
    float*          x2   = (float*)(ws + 54 * MB);           // [8192][512] f32
    float*          U    = (float*)(ws + 70 * MB);           // [8][32][64][64] f32
    unsigned short* Mx   = (unsigned short*)(ws + 74 * MB);  // [8][32][64][64] bf16
    unsigned short* P    = (unsigned short*)(ws + 76 * MB);  // 4 x [8192][512] bf16 partials (32 MiB)

    const bool splitk = ws_size >= (size_t)108 * MB;

    prep_kernel<<<7168, 256, 0, stream>>>(Wq, Wk, Wv, Wo, Wqb, W1, W1t, W2, W2t);

    ln_kernel<<<2048, 256, 0, stream>>>(x, ln1w, ln1b, hb);

    // fused QKV: [8192,512] @ [1536,512]^T, 256^2 tiles: grid (32,6)
    gemm256<0, 0><<<dim3(32, 6), 512, 0, stream>>>(hb, Wqb, 512, 512, 512, 1536,
                                                   QKVb, nullptr, 0);

    attn_u_kernel<<<dim3(32, 8), 256, 0, stream>>>(QKVb, U);
    attn_scan_kernel<<<dim3(16, 8), 256, 0, stream>>>(U, Mx);
    attn_y_kernel<<<dim3(32, 8), 256, 0, stream>>>(QKVb, Mx, Yb);

    // Wo projection + residual: 128-tile, grid (64,4)
    gemm_bt<1, 128><<<dim3(64, 4), 256, 0, stream>>>(Yb, Wqb + 3 * 262144, 512, 512, 512, 512,
                                                     nullptr, x2, nullptr, x);

    ln_kernel<<<2048, 256, 0, stream>>>(x2, ln2w, ln2b, hb);

    for (int lvl = 0; lvl < 3; ++lvl) {
        // up-proj 256^2: grid (32,8), XMAP=1 (B-panel per XCD)
        gemm256<2, 1><<<dim3(32, 8), 512, 0, stream>>>(hb, W1t + (size_t)lvl * 1048576,
                                                       512, 512, 512, 2048,
                                                       tb, b1 + lvl * 2048, 0);
        if (splitk) {
            // down-proj split-K4, 256^2: grid (32,2,4), XMAP=2 ((n,z)-panel per XCD)
            gemm256<5, 2><<<dim3(32, 2, 4), 512, 0, stream>>>(tb, W2t + (size_t)lvl * 1048576,
                                                              512, 2048, 2048, 512,
                                                              P, nullptr, (size_t)8192 * 512);
            if (lvl < 2)
                reduce_down<false><<<2048, 256, 0, stream>>>(P, b2 + lvl * 512, nullptr, hb, nullptr);
            else
                reduce_down<true><<<2048, 256, 0, stream>>>(P, b2 + lvl * 512, x2, nullptr, out);
        } else {
            gemm256<5, 0><<<dim3(32, 2, 1), 512, 0, stream>>>(tb, W2t + (size_t)lvl * 1048576,
                                                              2048, 2048, 2048, 512,
                                                              P, nullptr, 0);
            if (lvl < 2)
                reduce_down<false><<<2048, 256, 0, stream>>>(P, b2 + lvl * 512, nullptr, hb, nullptr);
            else
                reduce_down<true><<<2048, 256, 0, stream>>>(P, b2 + lvl * 512, x2, nullptr, out);
        }
    }
}

// Round 12
// 276.657 us; speedup vs baseline: 1.0450x; 1.0292x over previous
//
#include <hip/hip_runtime.h>
#include <hip/hip_bf16.h>
#include <cstdint>
#include <cstddef>

// ---------- types / helpers ----------
typedef __attribute__((ext_vector_type(8))) short bf16x8;
typedef __attribute__((ext_vector_type(4))) float f32x4;

#define MFMA16(a, b, c) __builtin_amdgcn_mfma_f32_16x16x32_bf16((a), (b), (c), 0, 0, 0)

static __device__ __forceinline__ unsigned short f2bf(float f) {
    union { float f; unsigned u; } v; v.f = f;
    unsigned r = v.u + 0x7fffu + ((v.u >> 16) & 1u);
    return (unsigned short)(r >> 16);
}

static __device__ __forceinline__ float bf2f(unsigned short u) {
    union { unsigned u; float f; } v; v.u = ((unsigned)u) << 16; return v.f;
}

static __device__ __forceinline__ float gelu_tanh(float x) {
    float z = 0.7978845608028654f * (x + 0.044715f * x * x * x);
    float a = fabsf(z);
    float e = __expf(-2.0f * a);
    float t = (1.0f - e) / (1.0f + e);
    t = (z < 0.0f) ? -t : t;
    return 0.5f * x * (1.0f + t);
}

static __device__ __forceinline__ void gload16(const void* g, void* l) {
    __builtin_amdgcn_global_load_lds((const __attribute__((address_space(1))) unsigned int*)g,
                                     (__attribute__((address_space(3))) unsigned int*)l,
                                     16, 0, 0);
}

// ---------- merged weight prep ----------
// blocks [0,1024): Wq|Wk|Wv|Wo f32 -> bf16 (4x262144 elems, 4/thread)
// blocks [1024,4096): W1 [3][512][2048] -> W1t [3][2048][512] bf16
// blocks [4096,7168): W2 [3][2048][512] -> W2t [3][512][2048] bf16
__global__ __launch_bounds__(256) void prep_kernel(
    const float* __restrict__ Wq, const float* __restrict__ Wk,
    const float* __restrict__ Wv, const float* __restrict__ Wo,
    unsigned short* __restrict__ Wqb,
    const float* __restrict__ W1, unsigned short* __restrict__ W1t,
    const float* __restrict__ W2, unsigned short* __restrict__ W2t) {
    int b = blockIdx.x;
    if (b < 1024) {
        int i = b * 256 + threadIdx.x;
        int idx = i * 4;
        int which = idx >> 18;
        int off = idx & 262143;
        const float* src = (which == 0) ? Wq : (which == 1) ? Wk : (which == 2) ? Wv : Wo;
        float4 v = *(const float4*)(src + off);
        unsigned long long p = (unsigned long long)f2bf(v.x) | ((unsigned long long)f2bf(v.y) << 16)
                             | ((unsigned long long)f2bf(v.z) << 32) | ((unsigned long long)f2bf(v.w) << 48);
        *(unsigned long long*)(Wqb + idx) = p;
        return;
    }
    __shared__ float tile[32][33];
    const float* in; unsigned short* out;
    int R, C, c0, r0;
    if (b < 4096) {
        int t = b - 1024; int lvl = t >> 10; int r = t & 1023;
        R = 512; C = 2048;
        in  = W1 + (size_t)lvl * R * C;  out = W1t + (size_t)lvl * R * C;
        c0 = (r & 63) * 32; r0 = (r >> 6) * 32;
    } else {
        int t = b - 4096; int lvl = t >> 10; int r = t & 1023;
        R = 2048; C = 512;
        in  = W2 + (size_t)lvl * R * C;  out = W2t + (size_t)lvl * R * C;
        c0 = (r & 15) * 32; r0 = (r >> 4) * 32;
    }
    int tx = threadIdx.x & 31, ty = threadIdx.x >> 5;
    #pragma unroll
    for (int ii = 0; ii < 4; ++ii) {
        int i = ty * 4 + ii;
        tile[i][tx] = in[(size_t)(r0 + i) * C + c0 + tx];
    }
    __syncthreads();
    #pragma unroll
    for (int jj = 0; jj < 4; ++jj) {
        int j = ty * 4 + jj;
        out[(size_t)(c0 + j) * R + r0 + tx] = f2bf(tile[tx][j]);
    }
}

// ---------- layernorm: f32 [rows][512] -> bf16 ----------
__global__ __launch_bounds__(256) void ln_kernel(const float* __restrict__ x,
                                                 const float* __restrict__ w,
                                                 const float* __restrict__ b,
                                                 unsigned short* __restrict__ out) {
    int tid = threadIdx.x, l = tid & 63, wv = tid >> 6;
    size_t row = (size_t)blockIdx.x * 4 + wv;
    const float* xr = x + row * 512 + l * 8;
    float4 v0 = *(const float4*)xr;
    float4 v1 = *(const float4*)(xr + 4);
    float vv[8] = {v0.x, v0.y, v0.z, v0.w, v1.x, v1.y, v1.z, v1.w};
    float s = 0.f, q = 0.f;
    #pragma unroll
    for (int j = 0; j < 8; ++j) { s += vv[j]; q += vv[j] * vv[j]; }
    #pragma unroll
    for (int off = 1; off < 64; off <<= 1) { s += __shfl_xor(s, off); q += __shfl_xor(q, off); }
    float mu = s * (1.0f / 512.0f);
    float rs = rsqrtf(q * (1.0f / 512.0f) - mu * mu + 1e-5f);
    union { unsigned short us[8]; uint4 u; } pk;
    #pragma unroll
    for (int j = 0; j < 8; ++j)
        pk.us[j] = f2bf((vv[j] - mu) * rs * w[l * 8 + j] + b[l * 8 + j]);
    *(uint4*)(out + row * 512 + l * 8) = pk.u;
}

// ---------- 256x256 GEMM (R8 2-phase prefetch dbuf; best measured) ----------
// 512 threads / 8 waves (2Mx4N), per-wave 128x64 C, BK=64, 128 KB LDS dbuf.
// EPI: 0 ->bf16 ; 2 +bias,gelu->bf16 ; 5 bf16 partial (split-K via blockIdx.z)
template<int EPI>
__global__ __launch_bounds__(512, 2) void gemm256(
    const unsigned short* __restrict__ A,
    const unsigned short* __restrict__ Bt,
    int K, int lda, int ldb, int N,
    unsigned short* __restrict__ outb,
    const float* __restrict__ bias,
    size_t planeStride) {
    __shared__ bf16x8 As[2][2048];
    __shared__ bf16x8 Bs[2][2048];
    const int tid = threadIdx.x, l = tid & 63, w = tid >> 6;
    const int m0 = blockIdx.x * 256, n0 = blockIdx.y * 256;
    const int wr = (w >> 2) * 128, wc = (w & 3) * 64;
    const int srow = l >> 3;
    const int scol = ((l & 7) ^ srow) * 8;

    if constexpr (EPI == 5) {
        size_t z = blockIdx.z;
        A    += z * (size_t)K;         // K = per-plane K; lda spans full row
        Bt   += z * (size_t)K;
        outb += z * planeStride;
    }

    const int nkt = K >> 6;
    auto stage = [&](int buf, int kt) {
        const unsigned short* Ag = A + (size_t)m0 * lda + kt * 64;
        const unsigned short* Bg = Bt + (size_t)n0 * ldb + kt * 64;
        #pragma unroll
        for (int i = 0; i < 4; ++i) {
            int chunk = i * 8 + w;
            int row = chunk * 8 + srow;
            gload16(Ag + (size_t)row * lda + scol, &As[buf][chunk * 64]);
            gload16(Bg + (size_t)row * ldb + scol, &Bs[buf][chunk * 64]);
        }
    };

    f32x4 acc[8][4] = {};
    stage(0, 0);
    __syncthreads();
    int cur = 0;
    for (int kt = 0; kt < nkt; ++kt) {
        if (kt + 1 < nkt) stage(cur ^ 1, kt + 1);
        #pragma unroll
        for (int kk = 0; kk < 2; ++kk) {
            bf16x8 af[8], bfr[4];
            #pragma unroll
            for (int mi = 0; mi < 8; ++mi) {
                int r = wr + mi * 16 + (l & 15);
                af[mi] = As[cur][r * 8 + ((kk * 4 + (l >> 4)) ^ (r & 7))];
            }
            #pragma unroll
            for (int ni = 0; ni < 4; ++ni) {
                int r = wc + ni * 16 + (l & 15);
                bfr[ni] = Bs[cur][r * 8 + ((kk * 4 + (l >> 4)) ^ (r & 7))];
            }
            #pragma unroll
            for (int mi = 0; mi < 8; ++mi)
                #pragma unroll
                for (int ni = 0; ni < 4; ++ni)
                    acc[mi][ni] = MFMA16(af[mi], bfr[ni], acc[mi][ni]);
        }
        __syncthreads();
        cur ^= 1;
    }

    #pragma unroll
    for (int mi = 0; mi < 8; ++mi)
        #pragma unroll
        for (int ni = 0; ni < 4; ++ni) {
            int col = n0 + wc + ni * 16 + (l & 15);
            #pragma unroll
            for (int r = 0; r < 4; ++r) {
                int row = m0 + wr + mi * 16 + (l >> 4) * 4 + r;
                float v = acc[mi][ni][r];
                size_t idx = (size_t)row * N + col;
                if constexpr (EPI == 0) {
                    outb[idx] = f2bf(v);
                } else if constexpr (EPI == 2) {
                    v += bias[col];
                    outb[idx] = f2bf(gelu_tanh(v));
                } else {
                    outb[idx] = f2bf(v);   // bf16 partial
                }
            }
        }
}

// ---------- 128-tile GEMM (Wo only): R2 structure ----------
template<int EPI, int TN>
__global__ __launch_bounds__(256) void gemm_bt(
    const unsigned short* __restrict__ A,
    const unsigned short* __restrict__ Bt,
    int K, int lda, int ldb, int N,
    unsigned short* __restrict__ outb,
    float* __restrict__ outf,
    const float* __restrict__ bias,
    const float* __restrict__ resid) {
    constexpr int NI = TN / 32;
    constexpr int BCH = TN / 32;
    __shared__ bf16x8 As[2][1024];
    __shared__ bf16x8 Bs[2][TN * 8];
    const int tid = threadIdx.x, l = tid & 63, w = tid >> 6;
    const int m0 = blockIdx.x * 128, n0 = blockIdx.y * TN;
    const int wr = (w >> 1) * 64, wc = (w & 1) * (TN / 2);
    const int srow = l >> 3;
    const int scol = ((l & 7) ^ srow) * 8;

    const int nkt = K >> 6;
    auto stage = [&](int buf, int kt) {
        const unsigned short* Ag = A + (size_t)m0 * lda + kt * 64;
        const unsigned short* Bg = Bt + (size_t)n0 * ldb + kt * 64;
        #pragma unroll
        for (int i = 0; i < 4; ++i) {
            int chunk = i * 4 + w;
            int row = chunk * 8 + srow;
            gload16(Ag + (size_t)row * lda + scol, &As[buf][chunk * 64]);
        }
        #pragma unroll
        for (int i = 0; i < BCH; ++i) {
            int chunk = i * 4 + w;
            int row = chunk * 8 + srow;
            gload16(Bg + (size_t)row * ldb + scol, &Bs[buf][chunk * 64]);
        }
    };

    f32x4 acc[4][NI] = {};
    stage(0, 0);
    __syncthreads();
    int cur = 0;
    for (int kt = 0; kt < nkt; ++kt) {
        if (kt + 1 < nkt) stage(cur ^ 1, kt + 1);
        #pragma unroll
        for (int kk = 0; kk < 2; ++kk) {
            bf16x8 af[4], bfr[NI];
            #pragma unroll
            for (int mi = 0; mi < 4; ++mi) {
                int r = wr + mi * 16 + (l & 15);
                af[mi] = As[cur][r * 8 + ((kk * 4 + (l >> 4)) ^ (r & 7))];
            }
            #pragma unroll
            for (int ni = 0; ni < NI; ++ni) {
                int r = wc + ni * 16 + (l & 15);
                bfr[ni] = Bs[cur][r * 8 + ((kk * 4 + (l >> 4)) ^ (r & 7))];
            }
            #pragma unroll
            for (int mi = 0; mi < 4; ++mi)
                #pragma unroll
                for (int ni = 0; ni < NI; ++ni)
                    acc[mi][ni] = MFMA16(af[mi], bfr[ni], acc[mi][ni]);
        }
        __syncthreads();
        cur ^= 1;
    }

    #pragma unroll
    for (int mi = 0; mi < 4; ++mi)
        #pragma unroll
        for (int ni = 0; ni < NI; ++ni) {
            int col = n0 + wc + ni * 16 + (l & 15);
            #pragma unroll
            for (int r = 0; r < 4; ++r) {
                int row = m0 + wr + mi * 16 + (l >> 4) * 4 + r;
                float v = acc[mi][ni][r];
                size_t idx = (size_t)row * N + col;
                if constexpr (EPI == 1) {
                    outf[idx] = v + resid[idx];
                } else {
                    outb[idx] = f2bf(v);
                }
            }
        }
}

// ---------- split-K4 reduce ----------
template<bool FINAL>
__global__ __launch_bounds__(256) void reduce_down(const unsigned short* __restrict__ P,
                                                   const float* __restrict__ bias,
                                                   const float* __restrict__ resid,
                                                   unsigned short* __restrict__ outb,
                                                   float* __restrict__ outf) {
    size_t i = ((size_t)blockIdx.x * 256 + threadIdx.x) * 8;
    int col = (int)(i & 511);
    bf16x8 a0 = *(const bf16x8*)(P + i);
    bf16x8 a1 = *(const bf16x8*)(P + 4194304 + i);
    bf16x8 a2 = *(const bf16x8*)(P + 2 * 4194304 + i);
    bf16x8 a3 = *(const bf16x8*)(P + 3 * 4194304 + i);
    float4 b0 = *(const float4*)(bias + col);
    float4 b1 = *(const float4*)(bias + col + 4);
    float bs[8] = {b0.x, b0.y, b0.z, b0.w, b1.x, b1.y, b1.z, b1.w};
    float v[8];
    #pragma unroll
    for (int j = 0; j < 8; ++j)
        v[j] = (bf2f((unsigned short)a0[j]) + bf2f((unsigned short)a1[j]))
             + (bf2f((unsigned short)a2[j]) + bf2f((unsigned short)a3[j])) + bs[j];
    if constexpr (FINAL) {
        const float4 r0 = *(const float4*)(resid + i);
        const float4 r1 = *(const float4*)(resid + i + 4);
        float4 o0 = {v[0] + r0.x, v[1] + r0.y, v[2] + r0.z, v[3] + r0.w};
        float4 o1 = {v[4] + r1.x, v[5] + r1.y, v[6] + r1.z, v[7] + r1.w};
        *(float4*)(outf + i) = o0;
        *(float4*)(outf + i + 4) = o1;
    } else {
        union { unsigned short us[8]; uint4 u; } pk;
        #pragma unroll
        for (int j = 0; j < 8; ++j) pk.us[j] = f2bf(v[j]);
        *(uint4*)(outb + i) = pk.u;
    }
}

// ---------- attention A1 ----------
__global__ __launch_bounds__(256) void attn_u_kernel(
    const unsigned short* __restrict__ QKV,
    float* __restrict__ U) {
    const int c = blockIdx.x, h = blockIdx.y;
    const int tid = threadIdx.x, l = tid & 63, w = tid >> 6;
    __shared__ __align__(16) unsigned short Kt[64 * 256];
    __shared__ __align__(16) unsigned short Vt[64 * 256];
    for (int i = 0; i < 8; ++i) {
        int idx = i * 256 + tid;
        int tr = idx >> 3, g = idx & 7;
        int bb = tr >> 6, tl = tr & 63;
        size_t go = (size_t)(bb * 2048 + c * 64 + tl) * 1536 + h * 64 + g * 8;
        bf16x8 kv = *(const bf16x8*)(QKV + go + 512);
        bf16x8 vv = *(const bf16x8*)(QKV + go + 1024);
        #pragma unroll
        for (int j = 0; j < 8; ++j) {
            int d = g * 8 + j;
            int ts = tr ^ ((d & 7) << 3);
            Kt[d * 256 + ts] = (unsigned short)kv[j];
            Vt[d * 256 + ts] = (unsigned short)vv[j];
        }
    }
    __syncthreads();
    const int dr = (w >> 1) * 32, kc = (w & 1) * 32;
    f32x4 acc[2][2] = {};
    #pragma unroll
    for (int kk = 0; kk < 8; ++kk) {
        bf16x8 av[2], bk[2];
        #pragma unroll
        for (int mi = 0; mi < 2; ++mi) {
            int r = dr + mi * 16 + (l & 15);
            av[mi] = *(const bf16x8*)&Vt[r * 256 + ((kk * 32 + (l >> 4) * 8) ^ ((r & 7) << 3))];
        }
        #pragma unroll
        for (int ni = 0; ni < 2; ++ni) {
            int r = kc + ni * 16 + (l & 15);
            bk[ni] = *(const bf16x8*)&Kt[r * 256 + ((kk * 32 + (l >> 4) * 8) ^ ((r & 7) << 3))];
        }
        #pragma unroll
        for (int mi = 0; mi < 2; ++mi)
            #pragma unroll
            for (int ni = 0; ni < 2; ++ni)
                acc[mi][ni] = MFMA16(av[mi], bk[ni], acc[mi][ni]);
    }
    float* Uo = U + (size_t)(h * 32 + c) * 4096;
    #pragma unroll
    for (int mi = 0; mi < 2; ++mi)
        #pragma unroll
        for (int ni = 0; ni < 2; ++ni)
            #pragma unroll
            for (int r = 0; r < 4; ++r) {
                int d = dr + mi * 16 + (l >> 4) * 4 + r;
                int k2 = kc + ni * 16 + (l & 15);
                Uo[d * 64 + k2] = acc[mi][ni][r] * 0.25f;
            }
}

// ---------- attention A2 ----------
__global__ __launch_bounds__(256) void attn_scan_kernel(const float* __restrict__ U,
                                                        unsigned short* __restrict__ Mx) {
    int e = blockIdx.x * 256 + threadIdx.x;
    int h = blockIdx.y;
    const float* Ub = U + (size_t)h * 32 * 4096 + e;
    unsigned short* Mb = Mx + (size_t)h * 32 * 4096 + e;
    float a = 0.0f;
    #pragma unroll
    for (int c0 = 0; c0 < 32; c0 += 4) {
        float u0 = Ub[(c0 + 0) * 4096];
        float u1 = Ub[(c0 + 1) * 4096];
        float u2 = Ub[(c0 + 2) * 4096];
        float u3 = Ub[(c0 + 3) * 4096];
        Mb[(c0 + 0) * 4096] = f2bf(a); a += u0;
        Mb[(c0 + 1) * 4096] = f2bf(a); a += u1;
        Mb[(c0 + 2) * 4096] = f2bf(a); a += u2;
        Mb[(c0 + 3) * 4096] = f2bf(a); a += u3;
    }
}

// ---------- attention A3 ----------
__global__ __launch_bounds__(256) void attn_y_kernel(
    const unsigned short* __restrict__ QKV,
    const unsigned short* __restrict__ Mx,
    unsigned short* __restrict__ Y) {
    const int c = blockIdx.x, h = blockIdx.y;
    const int tid = threadIdx.x, l = tid & 63, w = tid >> 6;  // w == query batch
    __shared__ __align__(16) unsigned short Vt[64 * 256];
    __shared__ __align__(16) unsigned short Ss[4][64 * 64];

    for (int i = 0; i < 8; ++i) {
        int idx = i * 256 + tid;
        int tr = idx >> 3, g = idx & 7;
        int bb = tr >> 6, tl = tr & 63;
        bf16x8 vv = *(const bf16x8*)(QKV + ((size_t)(bb * 2048 + c * 64 + tl) * 1536 + 1024 + h * 64 + g * 8));
        #pragma unroll
        for (int j = 0; j < 8; ++j) {
            int d = g * 8 + j;
            Vt[d * 256 + (tr ^ ((d & 7) << 3))] = (unsigned short)vv[j];
        }
    }
    __syncthreads();

    f32x4 yacc[4][4] = {};

    bf16x8 qf[2][4];
    #pragma unroll
    for (int kk = 0; kk < 2; ++kk)
        #pragma unroll
        for (int ni = 0; ni < 4; ++ni) {
            int qloc = ni * 16 + (l & 15);
            qf[kk][ni] = *(const bf16x8*)(QKV + ((size_t)(w * 2048 + c * 64 + qloc) * 1536
                                                + h * 64 + kk * 32 + (l >> 4) * 8));
        }

    const unsigned short* Mrow = Mx + (size_t)(h * 32 + c) * 4096;
    #pragma unroll
    for (int kk = 0; kk < 2; ++kk) {
        bf16x8 am[4];
        #pragma unroll
        for (int mi = 0; mi < 4; ++mi) {
            int d = mi * 16 + (l & 15);
            am[mi] = *(const bf16x8*)(Mrow + d * 64 + kk * 32 + (l >> 4) * 8);
        }
        #pragma unroll
        for (int mi = 0; mi < 4; ++mi)
            #pragma unroll
            for (int ni = 0; ni < 4; ++ni)
                yacc[mi][ni] = MFMA16(am[mi], qf[kk][ni], yacc[mi][ni]);
    }

    unsigned short* Sw = &Ss[w][0];
    for (int tv = 0; tv < 4; ++tv) {
        #pragma unroll
        for (int th = 0; th < 2; ++th) {
            f32x4 sacc[2][4] = {};
            #pragma unroll
            for (int kk = 0; kk < 2; ++kk) {
                bf16x8 ak[2];
                #pragma unroll
                for (int mi = 0; mi < 2; ++mi) {
                    int tloc = th * 32 + mi * 16 + (l & 15);
                    ak[mi] = *(const bf16x8*)(QKV + ((size_t)(tv * 2048 + c * 64 + tloc) * 1536
                                                    + 512 + h * 64 + kk * 32 + (l >> 4) * 8));
                }
                #pragma unroll
                for (int mi = 0; mi < 2; ++mi)
                    #pragma unroll
                    for (int ni = 0; ni < 4; ++ni)
                        sacc[mi][ni] = MFMA16(ak[mi], qf[kk][ni], sacc[mi][ni]);
            }
            #pragma unroll
            for (int mi = 0; mi < 2; ++mi)
                #pragma unroll
                for (int ni = 0; ni < 4; ++ni) {
                    int tb = th * 32 + mi * 16 + (l >> 4) * 4;
                    int qcol = ni * 16 + (l & 15);
                    unsigned long long p = 0;
                    #pragma unroll
                    for (int r = 0; r < 4; ++r) {
                        float v = (tb + r <= qcol) ? sacc[mi][ni][r] * 0.25f : 0.0f;
                        p |= ((unsigned long long)f2bf(v)) << (16 * r);
                    }
                    int ts = tb ^ ((qcol & 7) << 3);
                    *(unsigned long long*)(Sw + qcol * 64 + ts) = p;
                }
        }
        #pragma unroll
        for (int kk2 = 0; kk2 < 2; ++kk2) {
            bf16x8 av[4], bs[4];
            #pragma unroll
            for (int mi = 0; mi < 4; ++mi) {
                int d = mi * 16 + (l & 15);
                av[mi] = *(const bf16x8*)&Vt[d * 256 + ((tv * 64 + kk2 * 32 + (l >> 4) * 8) ^ ((d & 7) << 3))];
            }
            #pragma unroll
            for (int ni = 0; ni < 4; ++ni) {
                int q = ni * 16 + (l & 15);
                bs[ni] = *(const bf16x8*)&Sw[q * 64 + ((kk2 * 32 + (l >> 4) * 8) ^ ((q & 7) << 3))];
            }
            #pragma unroll
            for (int mi = 0; mi < 4; ++mi)
                #pragma unroll
                for (int ni = 0; ni < 4; ++ni)
                    yacc[mi][ni] = MFMA16(av[mi], bs[ni], yacc[mi][ni]);
        }
    }

    #pragma unroll
    for (int mi = 0; mi < 4; ++mi)
        #pragma unroll
        for (int ni = 0; ni < 4; ++ni) {
            int qloc = ni * 16 + (l & 15);
            int d0 = mi * 16 + (l >> 4) * 4;
            unsigned long long p = 0;
            #pragma unroll
            for (int r = 0; r < 4; ++r)
                p |= ((unsigned long long)f2bf(yacc[mi][ni][r])) << (16 * r);
            *(unsigned long long*)(Y + ((size_t)(w * 2048 + c * 64 + qloc) * 512 + h * 64 + d0)) = p;
        }
}

// ---------- launch ----------
extern "C" void kernel_launch(void* const* d_in, const int* in_sizes, int n_in,
                              void* d_out, int out_size, void* d_ws, size_t ws_size,
                              hipStream_t stream) {
    const float* x    = (const float*)d_in[0];
    const float* Wq   = (const float*)d_in[1];
    const float* Wk   = (const float*)d_in[2];
    const float* Wv   = (const float*)d_in[3];
    const float* Wo   = (const float*)d_in[4];
    const float* ln1w = (const float*)d_in[5];
    const float* ln1b = (const float*)d_in[6];
    const float* ln2w = (const float*)d_in[7];
    const float* ln2b = (const float*)d_in[8];
    const float* W1   = (const float*)d_in[9];
    const float* b1   = (const float*)d_in[10];
    const float* W2   = (const float*)d_in[11];
    const float* b2   = (const float*)d_in[12];
    float* out = (float*)d_out;
    char* ws = (char*)d_ws;
    const size_t MB = 1024 * 1024;
    unsigned short* Wqb  = (unsigned short*)(ws + 0 * MB);   // Wq|Wk|Wv|Wo bf16
    unsigned short* W1t  = (unsigned short*)(ws + 2 * MB);   // [3][2048][512] bf16
    unsigned short* W2t  = (unsigned short*)(ws + 8 * MB);   // [3][512][2048] bf16
    unsigned short* hb   = (unsigned short*)(ws + 14 * MB);  // [8192][512] bf16
    unsigned short* QKVb = (unsigned short*)(ws + 22 * MB);  // [8192][1536] bf16
    unsigned short* Yb   = (unsigned short*)(ws + 46 * MB);  // [8192][512] bf16
    unsigned short* tb   = (unsigned short*)(ws + 22 * MB);  // [8192][2048] bf16 (aliases QKV+Y)
    float*          x2   = (float*)(ws + 54 * MB);           // [8192][512] f32
    float*          U    = (float*)(ws + 70 * MB);           // [8][32][64][64] f32
    unsigned short* Mx   = (unsigned short*)(ws + 74 * MB);  // [8][32][64][64] bf16
    unsigned short* P    = (unsigned short*)(ws + 76 * MB);  // 4 x [8192][512] bf16 partials (32 MiB)

    const bool splitk = ws_size >= (size_t)108 * MB;

    prep_kernel<<<7168, 256, 0, stream>>>(Wq, Wk, Wv, Wo, Wqb, W1, W1t, W2, W2t);

    ln_kernel<<<2048, 256, 0, stream>>>(x, ln1w, ln1b, hb);

    // fused QKV: [8192,512] @ [1536,512]^T, 256^2 tiles: grid (32,6)
    gemm256<0><<<dim3(32, 6), 512, 0, stream>>>(hb, Wqb, 512, 512, 512, 1536,
                                                QKVb, nullptr, 0);

    attn_u_kernel<<<dim3(32, 8), 256, 0, stream>>>(QKVb, U);
    attn_scan_kernel<<<dim3(16, 8), 256, 0, stream>>>(U, Mx);
    attn_y_kernel<<<dim3(32, 8), 256, 0, stream>>>(QKVb, Mx, Yb);

    // Wo projection + residual: 128-tile, grid (64,4)
    gemm_bt<1, 128><<<dim3(64, 4), 256, 0, stream>>>(Yb, Wqb + 3 * 262144, 512, 512, 512, 512,
                                                     nullptr, x2, nullptr, x);

    ln_kernel<<<2048, 256, 0, stream>>>(x2, ln2w, ln2b, hb);

    for (int lvl = 0; lvl < 3; ++lvl) {
        // up-proj 256^2: grid (32,8) = 256 blocks
        gemm256<2><<<dim3(32, 8), 512, 0, stream>>>(hb, W1t + (size_t)lvl * 1048576,
                                                    512, 512, 512, 2048,
                                                    tb, b1 + lvl * 2048, 0);
        if (splitk) {
            // down-proj split-K4, 256^2: grid (32,2,4) = 256 blocks, K=512/plane
            gemm256<5><<<dim3(32, 2, 4), 512, 0, stream>>>(tb, W2t + (size_t)lvl * 1048576,
                                                           512, 2048, 2048, 512,
                                                           P, nullptr, (size_t)8192 * 512);
            if (lvl < 2)
                reduce_down<false><<<2048, 256, 0, stream>>>(P, b2 + lvl * 512, nullptr, hb, nullptr);
            else
                reduce_down<true><<<2048, 256, 0, stream>>>(P, b2 + lvl * 512, x2, nullptr, out);
        } else {
            gemm256<5><<<dim3(32, 2, 1), 512, 0, stream>>>(tb, W2t + (size_t)lvl * 1048576,
                                                           2048, 2048, 2048, 512,
                                                           P, nullptr, 0);
            if (lvl < 2)
                reduce_down<false><<<2048, 256, 0, stream>>>(P, b2 + lvl * 512, nullptr, hb, nullptr);
            else
                reduce_down<true><<<2048, 256, 0, stream>>>(P, b2 + lvl * 512, x2, nullptr, out);
        }
    }
}